// Round 8
// baseline (136.387 us; speedup 1.0000x reference)
//
#include <hip/hip_runtime.h>
#include <math.h>

#define FFT_N   4096
#define THREADS 256

// Byte-bank swizzle for float2 LDS: bank-pair index of float2 slot s is
// s&15. swz(i)=i^((i>>4)&15) is bijective and spreads every access pattern
// used below (A: t+256k, B: 256a+j+16k, C: 16t+k) EXACTLY uniformly:
// each 16-lane quarter-wave covers all 16 bank pairs once -> conflict-free
// ds_*_b64. LDS = 4096*8 = 32768 B.
__device__ __forceinline__ int swz(int i) { return i ^ ((i >> 4) & 15); }

// rev4: base-4 digit reversal within 16 (self-inverse). In-place DIF dft16
// leaves slot r holding spectral index REV[r]; all uses are compile-time.
#define REV(r) ((((r) & 3) << 2) | ((r) >> 2))

// gperm[16t + r] = G at local position 16t + REV(r),
// G(p) = ((W[k]+W[(N-k)%N])/2 + 1)/N, k = 3-digit base-16 reversal of p.
__global__ void setup_g_kernel(const float* __restrict__ fw, float* __restrict__ gperm) {
    int p = blockIdx.x * blockDim.x + threadIdx.x;
    if (p >= FFT_N) return;
    int r = p & 15;
    int local = (p & ~15) | REV(r);
    unsigned k = ((local & 15u) << 8) | ((unsigned)local & 0xF0u) | ((unsigned)local >> 8);
    float wk  = fw[k];
    float wnk = fw[(FFT_N - k) & (FFT_N - 1)];
    gperm[p] = (0.5f * (wk + wnk) + 1.0f) * (1.0f / (float)FFT_N);
}

__device__ __forceinline__ void cmul(float& xr, float& xi, float c, float s) {
    float tv = xr; xr = tv * c - xi * s; xi = tv * s + xi * c;
}

// forward radix-4 butterfly, in place: X1 = t1 - i*t3, X3 = t1 + i*t3
__device__ __forceinline__ void bfly4_f(float& ar, float& ai, float& br, float& bi,
                                        float& cr, float& ci, float& dr, float& di) {
    float t0r = ar + cr, t0i = ai + ci;
    float t1r = ar - cr, t1i = ai - ci;
    float t2r = br + dr, t2i = bi + di;
    float t3r = br - dr, t3i = bi - di;
    ar = t0r + t2r; ai = t0i + t2i;
    br = t1r + t3i; bi = t1i - t3r;
    cr = t0r - t2r; ci = t0i - t2i;
    dr = t1r - t3i; di = t1i + t3r;
}
// inverse radix-4 butterfly, in place: Y1 = t1 + i*t3, Y3 = t1 - i*t3
__device__ __forceinline__ void bfly4_i(float& ar, float& ai, float& br, float& bi,
                                        float& cr, float& ci, float& dr, float& di) {
    float t0r = ar + cr, t0i = ai + ci;
    float t1r = ar - cr, t1i = ai - ci;
    float t2r = br + dr, t2i = bi + di;
    float t3r = br - dr, t3i = bi - di;
    ar = t0r + t2r; ai = t0i + t2i;
    br = t1r - t3i; bi = t1i + t3r;
    cr = t0r - t2r; ci = t0i - t2i;
    dr = t1r + t3i; di = t1i - t3r;
}

// In-place forward DFT16 (DIF). Output: slot r holds X[REV(r)].
__device__ __forceinline__ void dft16_f(float xr[16], float xi[16]) {
    const float C1 = 0.9238795325112867f;   // cos(pi/8)
    const float S1 = 0.3826834323650898f;   // sin(pi/8)
    const float H  = 0.7071067811865476f;
    #pragma unroll
    for (int m = 0; m < 4; ++m)
        bfly4_f(xr[m],xi[m], xr[m+4],xi[m+4], xr[m+8],xi[m+8], xr[m+12],xi[m+12]);
    cmul(xr[5],  xi[5],   C1, -S1);
    cmul(xr[9],  xi[9],    H,  -H);
    cmul(xr[13], xi[13],  S1, -C1);
    cmul(xr[6],  xi[6],    H,  -H);
    cmul(xr[10], xi[10], 0.f, -1.f);
    cmul(xr[14], xi[14],  -H,  -H);
    cmul(xr[7],  xi[7],   S1, -C1);
    cmul(xr[11], xi[11],  -H,  -H);
    cmul(xr[15], xi[15], -C1,  S1);
    #pragma unroll
    for (int g = 0; g < 4; ++g)
        bfly4_f(xr[4*g],xi[4*g], xr[4*g+1],xi[4*g+1], xr[4*g+2],xi[4*g+2], xr[4*g+3],xi[4*g+3]);
}

// In-place inverse DFT16 (unnormalized). Input: slot r holds X[REV(r)].
// Output: slot n holds x[n] (natural).
__device__ __forceinline__ void idft16(float xr[16], float xi[16]) {
    const float C1 = 0.9238795325112867f;
    const float S1 = 0.3826834323650898f;
    const float H  = 0.7071067811865476f;
    #pragma unroll
    for (int g = 0; g < 4; ++g)
        bfly4_i(xr[4*g],xi[4*g], xr[4*g+1],xi[4*g+1], xr[4*g+2],xi[4*g+2], xr[4*g+3],xi[4*g+3]);
    cmul(xr[5],  xi[5],   C1,  S1);
    cmul(xr[9],  xi[9],    H,   H);
    cmul(xr[13], xi[13],  S1,  C1);
    cmul(xr[6],  xi[6],    H,   H);
    cmul(xr[10], xi[10], 0.f, 1.f);
    cmul(xr[14], xi[14],  -H,   H);
    cmul(xr[7],  xi[7],   S1,  C1);
    cmul(xr[11], xi[11],  -H,   H);
    cmul(xr[15], xi[15], -C1, -S1);
    #pragma unroll
    for (int m = 0; m < 4; ++m)
        bfly4_i(xr[m],xi[m], xr[m+4],xi[m+4], xr[m+8],xi[m+8], xr[m+12],xi[m+12]);
}

// apply w^{REV(r)} to slot r (i.e. power p -> slot REV(p)); binary-power
// chain, dependency depth ~5. w = (cos ang, sin ang).
__device__ __forceinline__ void twiddle_rev(float xr[16], float xi[16], float ang) {
    float s1, c1; __sincosf(ang, &s1, &c1);
    float c2 = c1*c1 - s1*s1, s2 = 2.f*c1*s1;
    float c3 = c2*c1 - s2*s1, s3 = c2*s1 + s2*c1;
    float c4 = c2*c2 - s2*s2, s4 = 2.f*c2*s2;
    cmul(xr[4],  xi[4],  c1, s1);
    cmul(xr[8],  xi[8],  c2, s2);
    cmul(xr[12], xi[12], c3, s3);
    float bc = c4, bs = s4;
    #pragma unroll
    for (int q = 1; q < 4; ++q) {
        cmul(xr[q], xi[q], bc, bs);
        { float ec = bc*c1 - bs*s1, es = bc*s1 + bs*c1; cmul(xr[4+q],  xi[4+q],  ec, es); }
        { float ec = bc*c2 - bs*s2, es = bc*s2 + bs*c2; cmul(xr[8+q],  xi[8+q],  ec, es); }
        { float ec = bc*c3 - bs*s3, es = bc*s3 + bs*c3; cmul(xr[12+q], xi[12+q], ec, es); }
        if (q < 3) { float nb = bc*c4 - bs*s4; bs = bc*s4 + bs*c4; bc = nb; }
    }
}

__global__ __launch_bounds__(THREADS, 4) void fourier_fft_kernel(
    const float* __restrict__ in, const float* __restrict__ gperm,
    const float* __restrict__ lw, float* __restrict__ out)
{
    __shared__ float2 sh[FFT_N];
    const int t = threadIdx.x;
    const long long pair = blockIdx.x;
    const float* r0 = in + pair * (2LL * FFT_N);
    const float* r1 = r0 + FFT_N;

    const float CFA = -6.28318530717958647692f / 4096.0f;
    const float CFB = -6.28318530717958647692f / 256.0f;

    float xr[16], xi[16];

    // load: thread t owns x[t + 256n] — coalesced
    #pragma unroll
    for (int n = 0; n < 16; ++n) {
        xr[n] = r0[t + 256*n];
        xi[n] = r1[t + 256*n];
    }

    // ---- forward stage A (L=4096, j=t): slot r holds A[REV(r)]
    dft16_f(xr, xi);
    twiddle_rev(xr, xi, CFA * (float)t);
    #pragma unroll
    for (int k = 0; k < 16; ++k) sh[swz(t + 256*k)] = make_float2(xr[REV(k)], xi[REV(k)]);
    __syncthreads();

    // ---- forward stage B (L=256, j=t&15)
    const int jb = t & 15;
    const int baseB = (t >> 4)*256 + jb;
    #pragma unroll
    for (int n = 0; n < 16; ++n) { float2 v = sh[swz(baseB + 16*n)]; xr[n] = v.x; xi[n] = v.y; }
    dft16_f(xr, xi);
    twiddle_rev(xr, xi, CFB * (float)jb);
    #pragma unroll
    for (int k = 0; k < 16; ++k) sh[swz(baseB + 16*k)] = make_float2(xr[REV(k)], xi[REV(k)]);
    __syncthreads();

    // ---- forward stage C + pointwise G + inverse stage C', all in registers
    #pragma unroll
    for (int n = 0; n < 16; ++n) { float2 v = sh[swz(16*t + n)]; xr[n] = v.x; xi[n] = v.y; }
    dft16_f(xr, xi);
    {
        const float4* gp = (const float4*)(gperm + 16*t);   // already REV-permuted
        #pragma unroll
        for (int q = 0; q < 4; ++q) {
            float4 g = gp[q];
            xr[4*q+0] *= g.x; xi[4*q+0] *= g.x;
            xr[4*q+1] *= g.y; xi[4*q+1] *= g.y;
            xr[4*q+2] *= g.z; xi[4*q+2] *= g.z;
            xr[4*q+3] *= g.w; xi[4*q+3] *= g.w;
        }
    }
    idft16(xr, xi);
    #pragma unroll
    for (int n = 0; n < 16; ++n) sh[swz(16*t + n)] = make_float2(xr[n], xi[n]);
    __syncthreads();

    // ---- inverse stage B': load digit-reversed, conj twiddle, idft16
    #pragma unroll
    for (int k = 0; k < 16; ++k) { float2 v = sh[swz(baseB + 16*k)]; xr[REV(k)] = v.x; xi[REV(k)] = v.y; }
    twiddle_rev(xr, xi, -CFB * (float)jb);
    idft16(xr, xi);
    #pragma unroll
    for (int n = 0; n < 16; ++n) sh[swz(baseB + 16*n)] = make_float2(xr[n], xi[n]);
    __syncthreads();

    // ---- inverse stage A' + epilogue straight from registers
    #pragma unroll
    for (int k = 0; k < 16; ++k) { float2 v = sh[swz(t + 256*k)]; xr[REV(k)] = v.x; xi[REV(k)] = v.y; }
    twiddle_rev(xr, xi, -CFA * (float)t);
    idft16(xr, xi);

    float* o0 = out + pair * (2LL * FFT_N);
    #pragma unroll
    for (int n = 0; n < 16; ++n) {
        int i = t + 256*n;
        float l = lw[i];
        o0[i]         = fmaxf(xr[n]*l, 0.0f);
        o0[FFT_N + i] = fmaxf(xi[n]*l, 0.0f);
    }
}

extern "C" void kernel_launch(void* const* d_in, const int* in_sizes, int n_in,
                              void* d_out, int out_size, void* d_ws, size_t ws_size,
                              hipStream_t stream) {
    const float* inputs = (const float*)d_in[0];
    const float* fw     = (const float*)d_in[1];
    const float* lw     = (const float*)d_in[2];
    float* out   = (float*)d_out;
    float* gperm = (float*)d_ws;   // 4096 floats = 16 KB scratch

    hipLaunchKernelGGL(setup_g_kernel, dim3(FFT_N / THREADS), dim3(THREADS), 0, stream,
                       fw, gperm);

    const int pairs = in_sizes[0] / (2 * FFT_N);   // 16384 rows -> 8192 pairs
    hipLaunchKernelGGL(fourier_fft_kernel, dim3(pairs), dim3(THREADS), 0, stream,
                       inputs, gperm, lw, out);
}

// Round 9
// 116.288 us; speedup vs baseline: 1.1728x; 1.1728x over previous
//
#include <hip/hip_runtime.h>
#include <math.h>

#define FFT_N   4096
#define THREADS 256
#define PADN    4352   // max pad4 index 4347

// Additive pad: pad4(i) = i + 4*(i>>6). Injective (monotone). Properties:
//  A (i=t+256k):   pad4 = [t+4*(t>>6)] + 272k          (linear in k -> ds imm offsets)
//  B (i=256a+j+16k): pad4 = [272a+j] + 16k+4*(k>>2)    (linear in k -> ds imm offsets)
//  C (i=16t+n):    pad4 = [16t+4*(t>>2)] + n           (contiguous, 16B-aligned -> b128)
// Banks: <=2-way on A/B (free), b128-minimum on C. Address VALU ~0 per access.
__device__ __forceinline__ int pad4(int i) { return i + 4 * (i >> 6); }

// rev4: base-4 digit reversal within 16 (self-inverse). In-place DIF dft16
// leaves slot r holding spectral index REV[r]; all uses are compile-time.
#define REV(r) ((((r) & 3) << 2) | ((r) >> 2))

// gperm[16t + r] = G at local position 16t + REV(r),
// G(p) = ((W[k]+W[(N-k)%N])/2 + 1)/N, k = 3-digit base-16 reversal of p.
__global__ void setup_g_kernel(const float* __restrict__ fw, float* __restrict__ gperm) {
    int p = blockIdx.x * blockDim.x + threadIdx.x;
    if (p >= FFT_N) return;
    int r = p & 15;
    int local = (p & ~15) | REV(r);
    unsigned k = ((local & 15u) << 8) | ((unsigned)local & 0xF0u) | ((unsigned)local >> 8);
    float wk  = fw[k];
    float wnk = fw[(FFT_N - k) & (FFT_N - 1)];
    gperm[p] = (0.5f * (wk + wnk) + 1.0f) * (1.0f / (float)FFT_N);
}

__device__ __forceinline__ void cmul(float& xr, float& xi, float c, float s) {
    float tv = xr; xr = tv * c - xi * s; xi = tv * s + xi * c;
}

// forward radix-4 butterfly, in place: X1 = t1 - i*t3, X3 = t1 + i*t3
__device__ __forceinline__ void bfly4_f(float& ar, float& ai, float& br, float& bi,
                                        float& cr, float& ci, float& dr, float& di) {
    float t0r = ar + cr, t0i = ai + ci;
    float t1r = ar - cr, t1i = ai - ci;
    float t2r = br + dr, t2i = bi + di;
    float t3r = br - dr, t3i = bi - di;
    ar = t0r + t2r; ai = t0i + t2i;
    br = t1r + t3i; bi = t1i - t3r;
    cr = t0r - t2r; ci = t0i - t2i;
    dr = t1r - t3i; di = t1i + t3r;
}
// inverse radix-4 butterfly, in place: Y1 = t1 + i*t3, Y3 = t1 - i*t3
__device__ __forceinline__ void bfly4_i(float& ar, float& ai, float& br, float& bi,
                                        float& cr, float& ci, float& dr, float& di) {
    float t0r = ar + cr, t0i = ai + ci;
    float t1r = ar - cr, t1i = ai - ci;
    float t2r = br + dr, t2i = bi + di;
    float t3r = br - dr, t3i = bi - di;
    ar = t0r + t2r; ai = t0i + t2i;
    br = t1r - t3i; bi = t1i + t3r;
    cr = t0r - t2r; ci = t0i - t2i;
    dr = t1r + t3i; di = t1i - t3r;
}

// In-place forward DFT16 (DIF). Output: slot r holds X[REV(r)].
__device__ __forceinline__ void dft16_f(float xr[16], float xi[16]) {
    const float C1 = 0.9238795325112867f;   // cos(pi/8)
    const float S1 = 0.3826834323650898f;   // sin(pi/8)
    const float H  = 0.7071067811865476f;
    #pragma unroll
    for (int m = 0; m < 4; ++m)
        bfly4_f(xr[m],xi[m], xr[m+4],xi[m+4], xr[m+8],xi[m+8], xr[m+12],xi[m+12]);
    cmul(xr[5],  xi[5],   C1, -S1);
    cmul(xr[9],  xi[9],    H,  -H);
    cmul(xr[13], xi[13],  S1, -C1);
    cmul(xr[6],  xi[6],    H,  -H);
    cmul(xr[10], xi[10], 0.f, -1.f);
    cmul(xr[14], xi[14],  -H,  -H);
    cmul(xr[7],  xi[7],   S1, -C1);
    cmul(xr[11], xi[11],  -H,  -H);
    cmul(xr[15], xi[15], -C1,  S1);
    #pragma unroll
    for (int g = 0; g < 4; ++g)
        bfly4_f(xr[4*g],xi[4*g], xr[4*g+1],xi[4*g+1], xr[4*g+2],xi[4*g+2], xr[4*g+3],xi[4*g+3]);
}

// In-place inverse DFT16 (unnormalized). Input: slot r holds X[REV(r)].
// Output: slot n holds x[n] (natural).
__device__ __forceinline__ void idft16(float xr[16], float xi[16]) {
    const float C1 = 0.9238795325112867f;
    const float S1 = 0.3826834323650898f;
    const float H  = 0.7071067811865476f;
    #pragma unroll
    for (int g = 0; g < 4; ++g)
        bfly4_i(xr[4*g],xi[4*g], xr[4*g+1],xi[4*g+1], xr[4*g+2],xi[4*g+2], xr[4*g+3],xi[4*g+3]);
    cmul(xr[5],  xi[5],   C1,  S1);
    cmul(xr[9],  xi[9],    H,   H);
    cmul(xr[13], xi[13],  S1,  C1);
    cmul(xr[6],  xi[6],    H,   H);
    cmul(xr[10], xi[10], 0.f, 1.f);
    cmul(xr[14], xi[14],  -H,   H);
    cmul(xr[7],  xi[7],   S1,  C1);
    cmul(xr[11], xi[11],  -H,   H);
    cmul(xr[15], xi[15], -C1, -S1);
    #pragma unroll
    for (int m = 0; m < 4; ++m)
        bfly4_i(xr[m],xi[m], xr[m+4],xi[m+4], xr[m+8],xi[m+8], xr[m+12],xi[m+12]);
}

// apply w^{REV(r)} to slot r (i.e. power p -> slot REV(p)); binary-power
// chain, dependency depth ~5. w = (cos ang, sin ang).
__device__ __forceinline__ void twiddle_rev(float xr[16], float xi[16], float ang) {
    float s1, c1; __sincosf(ang, &s1, &c1);
    float c2 = c1*c1 - s1*s1, s2 = 2.f*c1*s1;
    float c3 = c2*c1 - s2*s1, s3 = c2*s1 + s2*c1;
    float c4 = c2*c2 - s2*s2, s4 = 2.f*c2*s2;
    cmul(xr[4],  xi[4],  c1, s1);
    cmul(xr[8],  xi[8],  c2, s2);
    cmul(xr[12], xi[12], c3, s3);
    float bc = c4, bs = s4;
    #pragma unroll
    for (int q = 1; q < 4; ++q) {
        cmul(xr[q], xi[q], bc, bs);
        { float ec = bc*c1 - bs*s1, es = bc*s1 + bs*c1; cmul(xr[4+q],  xi[4+q],  ec, es); }
        { float ec = bc*c2 - bs*s2, es = bc*s2 + bs*c2; cmul(xr[8+q],  xi[8+q],  ec, es); }
        { float ec = bc*c3 - bs*s3, es = bc*s3 + bs*c3; cmul(xr[12+q], xi[12+q], ec, es); }
        if (q < 3) { float nb = bc*c4 - bs*s4; bs = bc*s4 + bs*c4; bc = nb; }
    }
}

__global__ __launch_bounds__(THREADS, 4) void fourier_fft_kernel(
    const float* __restrict__ in, const float* __restrict__ gperm,
    const float* __restrict__ lw, float* __restrict__ out)
{
    __shared__ float re[PADN];
    __shared__ float im[PADN];
    const int t = threadIdx.x;
    const long long pair = blockIdx.x;
    const float* r0 = in + pair * (2LL * FFT_N);
    const float* r1 = r0 + FFT_N;

    const float CFA = -6.28318530717958647692f / 4096.0f;
    const float CFB = -6.28318530717958647692f / 256.0f;

    // per-thread LDS bases (computed once; all per-k offsets are immediates)
    const int baseA = t + 4 * (t >> 6);                        // + 272k
    const int baseB = 272 * (t >> 4) + (t & 15);               // + 16k + 4*(k>>2)
    const int baseC = 16 * t + 4 * (t >> 2);                   // + n (16B-aligned)
    const int jb = t & 15;

    float xr[16], xi[16];

    // load: thread t owns x[t + 256n] — coalesced
    #pragma unroll
    for (int n = 0; n < 16; ++n) {
        xr[n] = r0[t + 256*n];
        xi[n] = r1[t + 256*n];
    }

    // ---- forward stage A (L=4096, j=t): slot r holds A[REV(r)]
    dft16_f(xr, xi);
    twiddle_rev(xr, xi, CFA * (float)t);
    #pragma unroll
    for (int k = 0; k < 16; ++k) {
        int s = baseA + 272*k;
        re[s] = xr[REV(k)]; im[s] = xi[REV(k)];
    }
    __syncthreads();

    // ---- forward stage B (L=256, j=t&15)
    #pragma unroll
    for (int n = 0; n < 16; ++n) {
        int s = baseB + 16*n + 4*(n>>2);
        xr[n] = re[s]; xi[n] = im[s];
    }
    dft16_f(xr, xi);
    twiddle_rev(xr, xi, CFB * (float)jb);
    #pragma unroll
    for (int k = 0; k < 16; ++k) {
        int s = baseB + 16*k + 4*(k>>2);
        re[s] = xr[REV(k)]; im[s] = xi[REV(k)];
    }
    __syncthreads();

    // ---- forward stage C + pointwise G + inverse stage C', all in registers.
    // contiguous 16 floats per array -> 4x ds_read_b128 / 4x ds_write_b128 each
    #pragma unroll
    for (int q = 0; q < 4; ++q) {
        float4 vr = *(const float4*)&re[baseC + 4*q];
        float4 vi = *(const float4*)&im[baseC + 4*q];
        xr[4*q+0] = vr.x; xr[4*q+1] = vr.y; xr[4*q+2] = vr.z; xr[4*q+3] = vr.w;
        xi[4*q+0] = vi.x; xi[4*q+1] = vi.y; xi[4*q+2] = vi.z; xi[4*q+3] = vi.w;
    }
    dft16_f(xr, xi);
    {
        const float4* gp = (const float4*)(gperm + 16*t);   // already REV-permuted
        #pragma unroll
        for (int q = 0; q < 4; ++q) {
            float4 g = gp[q];
            xr[4*q+0] *= g.x; xi[4*q+0] *= g.x;
            xr[4*q+1] *= g.y; xi[4*q+1] *= g.y;
            xr[4*q+2] *= g.z; xi[4*q+2] *= g.z;
            xr[4*q+3] *= g.w; xi[4*q+3] *= g.w;
        }
    }
    idft16(xr, xi);
    #pragma unroll
    for (int q = 0; q < 4; ++q) {
        *(float4*)&re[baseC + 4*q] = make_float4(xr[4*q+0], xr[4*q+1], xr[4*q+2], xr[4*q+3]);
        *(float4*)&im[baseC + 4*q] = make_float4(xi[4*q+0], xi[4*q+1], xi[4*q+2], xi[4*q+3]);
    }
    __syncthreads();

    // ---- inverse stage B': load digit-reversed, conj twiddle, idft16
    #pragma unroll
    for (int k = 0; k < 16; ++k) {
        int s = baseB + 16*k + 4*(k>>2);
        xr[REV(k)] = re[s]; xi[REV(k)] = im[s];
    }
    twiddle_rev(xr, xi, -CFB * (float)jb);
    idft16(xr, xi);
    #pragma unroll
    for (int n = 0; n < 16; ++n) {
        int s = baseB + 16*n + 4*(n>>2);
        re[s] = xr[n]; im[s] = xi[n];
    }
    __syncthreads();

    // ---- inverse stage A' + epilogue straight from registers
    #pragma unroll
    for (int k = 0; k < 16; ++k) {
        int s = baseA + 272*k;
        xr[REV(k)] = re[s]; xi[REV(k)] = im[s];
    }
    twiddle_rev(xr, xi, -CFA * (float)t);
    idft16(xr, xi);

    float* o0 = out + pair * (2LL * FFT_N);
    #pragma unroll
    for (int n = 0; n < 16; ++n) {
        int i = t + 256*n;
        float l = lw[i];
        o0[i]         = fmaxf(xr[n]*l, 0.0f);
        o0[FFT_N + i] = fmaxf(xi[n]*l, 0.0f);
    }
}

extern "C" void kernel_launch(void* const* d_in, const int* in_sizes, int n_in,
                              void* d_out, int out_size, void* d_ws, size_t ws_size,
                              hipStream_t stream) {
    const float* inputs = (const float*)d_in[0];
    const float* fw     = (const float*)d_in[1];
    const float* lw     = (const float*)d_in[2];
    float* out   = (float*)d_out;
    float* gperm = (float*)d_ws;   // 4096 floats = 16 KB scratch

    hipLaunchKernelGGL(setup_g_kernel, dim3(FFT_N / THREADS), dim3(THREADS), 0, stream,
                       fw, gperm);

    const int pairs = in_sizes[0] / (2 * FFT_N);   // 16384 rows -> 8192 pairs
    hipLaunchKernelGGL(fourier_fft_kernel, dim3(pairs), dim3(THREADS), 0, stream,
                       inputs, gperm, lw, out);
}